// Round 22
// baseline (1046.210 us; speedup 1.0000x reference)
//
#include <hip/hip_runtime.h>

#define Bsz  256
#define Tlen 2048
#define Hdim 128

typedef __fp16 hf2 __attribute__((ext_vector_type(2)));
typedef __fp16 hf8 __attribute__((ext_vector_type(8)));
typedef float  f32x4 __attribute__((ext_vector_type(4)));

// Raw-HW transcendentals (VOP1, ~1 ulp). R12-verified win.
__device__ __forceinline__ float fexp2_(float x) {
    float r; asm("v_exp_f32 %0, %1" : "=v"(r) : "v"(x)); return r;
}
__device__ __forceinline__ float frcp_(float x) {
    float r; asm("v_rcp_f32 %0, %1" : "=v"(r) : "v"(x)); return r;
}
__device__ __forceinline__ float sigmoidf_(float v) {
    return frcp_(1.0f + fexp2_(v * -1.44269504f));
}
__device__ __forceinline__ float tanhf_(float v) {
    return 1.0f - 2.0f * frcp_(fexp2_(v * 2.88539008f) + 1.0f);
}

// pack 8 consecutive f32 into a v8f16 MFMA fragment slice
__device__ __forceinline__ hf8 pack8(const float* p) {
    union { hf2 h2[4]; hf8 h8; } u;
    u.h2[0] = __builtin_amdgcn_cvt_pkrtz(p[0], p[1]);
    u.h2[1] = __builtin_amdgcn_cvt_pkrtz(p[2], p[3]);
    u.h2[2] = __builtin_amdgcn_cvt_pkrtz(p[4], p[5]);
    u.h2[3] = __builtin_amdgcn_cvt_pkrtz(p[6], p[7]);
    return u.h8;
}
__device__ __forceinline__ hf8 bch8(float4 v) { return __builtin_bit_cast(hf8, v); }

#define MFMA(D, A, B) D = __builtin_amdgcn_mfma_f32_16x16x32_f16(A, B, D, 0, 0, 0)

struct Smem {
    float  x[Tlen];       // staged input row
    float  xh[Tlen];      // staged xh outputs
    __fp16 h[2][Hdim];    // double-buffered hidden state (f16)
};

// grid = 256 blocks (1 batch row each), block = 256 threads (4 waves).
// R22: wave-count halving. R21's per-step DS-pipe occupancy (~430 cyc: 8 waves
// x 256B redundant h-fetch + writes on the per-CU LDS pipe) and 8-wave barrier
// skew were first-order. Now 4 waves, each owning TWO unit-tiles:
//   wave w -> units w*32+m (tile a) and w*32+16+m (tile b).
// Per wave: 24 gate MFMAs + 4 xp MFMAs (xp redundancy 8x -> 4x), unpredicated
// gate math for 2 units/lane (independent, interleavable chains), one 32-lane
// contiguous ds_write_b16. DS traffic and barrier width both halve.
// Uniform-A (every row = h; R21-verified), B = W^T tiles, D reg 0 valid on all
// lanes (col = lane&15). Weights MFMA-only -> AGPR-native, no copy churn.
__global__ __launch_bounds__(256, 1)
void rnn_imp_kernel(const float* __restrict__ x,     // [B, T] (I=1)
                    const float* __restrict__ Wih,   // [384]
                    const float* __restrict__ Whh,   // [384, 128] gate-major (r,z,n)
                    const float* __restrict__ bih,   // [384]
                    const float* __restrict__ bhh,   // [384]
                    const float* __restrict__ Wfc,   // [128]
                    const float* __restrict__ bfc,   // [1]
                    float* __restrict__ out_newin,   // [T, B]
                    float* __restrict__ out_pred)    // [B, T-1]
{
    __shared__ __align__(128) Smem sm;

    const int tid  = threadIdx.x;
    const int b    = blockIdx.x;
    const int wave = tid >> 6;
    const int lane = tid & 63;
    const int m    = lane & 15;      // B/D column = unit-in-tile
    const int q    = lane >> 4;      // k-subchunk

    // stage x row (coalesced); zero h buffer 0
    for (int i = tid; i < Tlen; i += 256) sm.x[i] = x[b * Tlen + i];
    if (tid < Hdim) sm.h[0][tid] = (__fp16)0.0f;

    // ---- B fragments: W^T tiles for BOTH unit-tiles (MFMA-only -> AGPR) ----
    const int ua = wave * 32 + m;            // tile a unit
    const int ub = ua + 16;                  // tile b unit
    const int ko = q * 8;
    hf8 Ar0, Ar1, Ar2, Ar3, Az0, Az1, Az2, Az3, An0, An1, An2, An3;  // tile a
    hf8 Cr0, Cr1, Cr2, Cr3, Cz0, Cz1, Cz2, Cz3, Cn0, Cn1, Cn2, Cn3;  // tile b
    hf8 Bf0, Bf1, Bf2, Bf3;                                           // Wfc
    Ar0 = pack8(Whh + (ua +   0) * Hdim + 0  + ko);  Ar1 = pack8(Whh + (ua +   0) * Hdim + 32 + ko);
    Ar2 = pack8(Whh + (ua +   0) * Hdim + 64 + ko);  Ar3 = pack8(Whh + (ua +   0) * Hdim + 96 + ko);
    Az0 = pack8(Whh + (ua + 128) * Hdim + 0  + ko);  Az1 = pack8(Whh + (ua + 128) * Hdim + 32 + ko);
    Az2 = pack8(Whh + (ua + 128) * Hdim + 64 + ko);  Az3 = pack8(Whh + (ua + 128) * Hdim + 96 + ko);
    An0 = pack8(Whh + (ua + 256) * Hdim + 0  + ko);  An1 = pack8(Whh + (ua + 256) * Hdim + 32 + ko);
    An2 = pack8(Whh + (ua + 256) * Hdim + 64 + ko);  An3 = pack8(Whh + (ua + 256) * Hdim + 96 + ko);
    Cr0 = pack8(Whh + (ub +   0) * Hdim + 0  + ko);  Cr1 = pack8(Whh + (ub +   0) * Hdim + 32 + ko);
    Cr2 = pack8(Whh + (ub +   0) * Hdim + 64 + ko);  Cr3 = pack8(Whh + (ub +   0) * Hdim + 96 + ko);
    Cz0 = pack8(Whh + (ub + 128) * Hdim + 0  + ko);  Cz1 = pack8(Whh + (ub + 128) * Hdim + 32 + ko);
    Cz2 = pack8(Whh + (ub + 128) * Hdim + 64 + ko);  Cz3 = pack8(Whh + (ub + 128) * Hdim + 96 + ko);
    Cn0 = pack8(Whh + (ub + 256) * Hdim + 0  + ko);  Cn1 = pack8(Whh + (ub + 256) * Hdim + 32 + ko);
    Cn2 = pack8(Whh + (ub + 256) * Hdim + 64 + ko);  Cn3 = pack8(Whh + (ub + 256) * Hdim + 96 + ko);
    Bf0 = pack8(Wfc + 0  + ko);  Bf1 = pack8(Wfc + 32 + ko);
    Bf2 = pack8(Wfc + 64 + ko);  Bf3 = pack8(Wfc + 96 + ko);

    // gate constants for both units
    const float wihra = Wih[ua], wihza = Wih[ua + 128], wihna = Wih[ua + 256];
    const float wihrb = Wih[ub], wihzb = Wih[ub + 128], wihnb = Wih[ub + 256];
    const float bbra = bih[ua]       + bhh[ua];
    const float bbza = bih[ua + 128] + bhh[ua + 128];
    const float bina = bih[ua + 256];
    const float bhna = bhh[ua + 256];
    const float bbrb = bih[ub]       + bhh[ub];
    const float bbzb = bih[ub + 128] + bhh[ub + 128];
    const float binb = bih[ub + 256];
    const float bhnb = bhh[ub + 256];
    const float bfc0 = bfc[0];
    float hoa = 0.0f, hob = 0.0f;

    // h write: lanes 0-31 write contiguous units wave*32 + lane
    const int wrofs = wave * 32 + lane;

    __syncthreads();

#pragma unroll 1
    for (int t = 0; t < Tlen; ++t) {
        float xt = sm.x[t];   // early: latency hides under MFMAs

        // A fragments: every row = h (uniform broadcast reads, 256 B/wave)
        const float4* hp = (const float4*)sm.h[t & 1];
        hf8 A0 = bch8(hp[0 * 4 + q]);
        hf8 A1 = bch8(hp[1 * 4 + q]);
        hf8 A2 = bch8(hp[2 * 4 + q]);
        hf8 A3 = bch8(hp[3 * 4 + q]);

        f32x4 Dra = {0.f,0.f,0.f,0.f}, Dza = {0.f,0.f,0.f,0.f}, Dna = {0.f,0.f,0.f,0.f};
        f32x4 Drb = {0.f,0.f,0.f,0.f}, Dzb = {0.f,0.f,0.f,0.f}, Dnb = {0.f,0.f,0.f,0.f};
        f32x4 Dxp = {0.f,0.f,0.f,0.f};
        MFMA(Dxp, A0, Bf0); MFMA(Dra, A0, Ar0); MFMA(Dza, A0, Az0); MFMA(Dna, A0, An0);
        MFMA(Drb, A0, Cr0); MFMA(Dzb, A0, Cz0); MFMA(Dnb, A0, Cn0);
        MFMA(Dxp, A1, Bf1); MFMA(Dra, A1, Ar1); MFMA(Dza, A1, Az1); MFMA(Dna, A1, An1);
        MFMA(Drb, A1, Cr1); MFMA(Dzb, A1, Cz1); MFMA(Dnb, A1, Cn1);
        MFMA(Dxp, A2, Bf2); MFMA(Dra, A2, Ar2); MFMA(Dza, A2, Az2); MFMA(Dna, A2, An2);
        MFMA(Drb, A2, Cr2); MFMA(Dzb, A2, Cz2); MFMA(Dnb, A2, Cn2);
        MFMA(Dxp, A3, Bf3); MFMA(Dra, A3, Ar3); MFMA(Dza, A3, Az3); MFMA(Dna, A3, An3);
        MFMA(Drb, A3, Cr3); MFMA(Dzb, A3, Cz3); MFMA(Dnb, A3, Cn3);

        // gates: unpredicated, two independent unit-chains interleave
        float xp  = Dxp[0];
        float xh  = xp + bfc0;
        float cur = ((xt == 128.0f) && (t != 0)) ? xh : xt;

        float ra  = sigmoidf_(wihra * cur + bbra + Dra[0]);
        float rb  = sigmoidf_(wihrb * cur + bbrb + Drb[0]);
        float za  = sigmoidf_(wihza * cur + bbza + Dza[0]);
        float zb  = sigmoidf_(wihzb * cur + bbzb + Dzb[0]);
        float na  = tanhf_(wihna * cur + bina + ra * (Dna[0] + bhna));
        float nb  = tanhf_(wihnb * cur + binb + rb * (Dnb[0] + bhnb));
        float hna = (1.0f - za) * na + za * hoa;
        float hnb = (1.0f - zb) * nb + zb * hob;
        hoa = hna; hob = hnb;

        if (lane < 32) {
            float hv = (lane < 16) ? hna : hnb;
            // lanes 0-15 hold unit ua=w*32+m in hna; lanes 16-31 hold
            // ub=w*32+16+m in hnb; both equal w*32+lane's unit value
            sm.h[(t + 1) & 1][wrofs] = (__fp16)hv;
        }
        if (tid == 0) sm.xh[t] = xh;
        __syncthreads();
    }

    // bulk flush; cur reconstructed from pristine x + xh
    for (int i = tid; i < Tlen; i += 256) {
        float xv = sm.x[i];
        float cv = ((xv == 128.0f) && (i != 0)) ? sm.xh[i] : xv;
        out_newin[i * Bsz + b] = cv;
    }
    for (int i = tid; i < Tlen - 1; i += 256)
        out_pred[b * (Tlen - 1) + i] = sm.xh[i + 1];
}

extern "C" void kernel_launch(void* const* d_in, const int* in_sizes, int n_in,
                              void* d_out, int out_size, void* d_ws, size_t ws_size,
                              hipStream_t stream) {
    const float* x   = (const float*)d_in[0];
    const float* Wih = (const float*)d_in[1];
    const float* Whh = (const float*)d_in[2];
    const float* bih = (const float*)d_in[3];
    const float* bhh = (const float*)d_in[4];
    const float* Wfc = (const float*)d_in[5];
    const float* bfc = (const float*)d_in[6];

    float* out_newin = (float*)d_out;                 // [T*B] = 524288
    float* out_pred  = out_newin + Tlen * Bsz;        // [B*(T-1)] = 524032

    rnn_imp_kernel<<<Bsz, 256, 0, stream>>>(x, Wih, Whh, bih, bhh, Wfc, bfc,
                                            out_newin, out_pred);
}

// Round 23
// 994.879 us; speedup vs baseline: 1.0516x; 1.0516x over previous
//
#include <hip/hip_runtime.h>

#define Bsz  256
#define Tlen 2048
#define Hdim 128

typedef __fp16 hf2 __attribute__((ext_vector_type(2)));
typedef __fp16 hf8 __attribute__((ext_vector_type(8)));
typedef float  f32x4 __attribute__((ext_vector_type(4)));

// Raw-HW transcendentals (VOP1, ~1 ulp). R12-verified win.
__device__ __forceinline__ float fexp2_(float x) {
    float r; asm("v_exp_f32 %0, %1" : "=v"(r) : "v"(x)); return r;
}
__device__ __forceinline__ float frcp_(float x) {
    float r; asm("v_rcp_f32 %0, %1" : "=v"(r) : "v"(x)); return r;
}
__device__ __forceinline__ float sigmoidf_(float v) {
    return frcp_(1.0f + fexp2_(v * -1.44269504f));
}
__device__ __forceinline__ float tanhf_(float v) {
    return 1.0f - 2.0f * frcp_(fexp2_(v * 2.88539008f) + 1.0f);
}

// pack 8 consecutive f32 into a v8f16 MFMA fragment slice
__device__ __forceinline__ hf8 pack8(const float* p) {
    union { hf2 h2[4]; hf8 h8; } u;
    u.h2[0] = __builtin_amdgcn_cvt_pkrtz(p[0], p[1]);
    u.h2[1] = __builtin_amdgcn_cvt_pkrtz(p[2], p[3]);
    u.h2[2] = __builtin_amdgcn_cvt_pkrtz(p[4], p[5]);
    u.h2[3] = __builtin_amdgcn_cvt_pkrtz(p[6], p[7]);
    return u.h8;
}
__device__ __forceinline__ hf8 bch8(float4 v) { return __builtin_bit_cast(hf8, v); }

#define MFMA(D, A, B) D = __builtin_amdgcn_mfma_f32_16x16x32_f16(A, B, D, 0, 0, 0)

struct Smem {
    float  x[Tlen];       // staged input row
    float  xh[Tlen];      // staged xh outputs
    __fp16 h[2][Hdim];    // double-buffered hidden state (f16)
};

// grid = 256 blocks (1 batch row each), block = 512 threads (8 waves).
// R23 = R21 (champion, 929 us: uniform-A MFMA, 1 barrier/step, unpredicated
// gates, 2 waves/SIMD — R22 proved 1 wave/SIMD loses ~35% to exposed latency)
// + SPLIT ACCUMULATORS: each D-tile now uses two independent half-chains
// (chunks 0-1, 2-3) summed once at the end. MFMA dependent-chain depth 4 -> 2
// (~60-100 cyc off the barrier-aligned critical path that wave overlap cannot
// hide). xp half-chains issue first so cur resolves earliest.
// Layouts (R18-R21 HW-verified): B: lane l reg j = W[tile*16+(l&15)]
// [c*32+(l>>4)*8+j]; D: col = lane&15, reg 0 valid on all lanes (uniform A).
__global__ __launch_bounds__(512, 2)
void rnn_imp_kernel(const float* __restrict__ x,     // [B, T] (I=1)
                    const float* __restrict__ Wih,   // [384]
                    const float* __restrict__ Whh,   // [384, 128] gate-major (r,z,n)
                    const float* __restrict__ bih,   // [384]
                    const float* __restrict__ bhh,   // [384]
                    const float* __restrict__ Wfc,   // [128]
                    const float* __restrict__ bfc,   // [1]
                    float* __restrict__ out_newin,   // [T, B]
                    float* __restrict__ out_pred)    // [B, T-1]
{
    __shared__ __align__(128) Smem sm;

    const int tid  = threadIdx.x;
    const int b    = blockIdx.x;
    const int wave = tid >> 6;
    const int lane = tid & 63;
    const int m    = lane & 15;      // B/D column = unit-in-tile
    const int q    = lane >> 4;      // k-subchunk

    // stage x row (coalesced); zero h buffer 0
    for (int i = tid; i < Tlen; i += 512) sm.x[i] = x[b * Tlen + i];
    if (tid < Hdim) sm.h[0][tid] = (__fp16)0.0f;

    // ---- B fragments: W^T tiles (consumed only by MFMA -> AGPR-native) ----
    const int r0 = wave * 16 + m;            // unit row, gate r
    const int r1 = r0 + 128;                 // gate z
    const int r2 = r0 + 256;                 // gate n
    const int ko = q * 8;
    hf8 Br0, Br1, Br2, Br3, Bz0, Bz1, Bz2, Bz3,
        Bn0, Bn1, Bn2, Bn3, Bf0, Bf1, Bf2, Bf3;
    Br0 = pack8(Whh + r0 * Hdim + 0  + ko);  Br1 = pack8(Whh + r0 * Hdim + 32 + ko);
    Br2 = pack8(Whh + r0 * Hdim + 64 + ko);  Br3 = pack8(Whh + r0 * Hdim + 96 + ko);
    Bz0 = pack8(Whh + r1 * Hdim + 0  + ko);  Bz1 = pack8(Whh + r1 * Hdim + 32 + ko);
    Bz2 = pack8(Whh + r1 * Hdim + 64 + ko);  Bz3 = pack8(Whh + r1 * Hdim + 96 + ko);
    Bn0 = pack8(Whh + r2 * Hdim + 0  + ko);  Bn1 = pack8(Whh + r2 * Hdim + 32 + ko);
    Bn2 = pack8(Whh + r2 * Hdim + 64 + ko);  Bn3 = pack8(Whh + r2 * Hdim + 96 + ko);
    // Wfc in ALL columns: every lane's D3 reg 0 = xp (R20-verified)
    Bf0 = pack8(Wfc + 0  + ko);  Bf1 = pack8(Wfc + 32 + ko);
    Bf2 = pack8(Wfc + 64 + ko);  Bf3 = pack8(Wfc + 96 + ko);

    // gate constants for this lane's column unit (valid on all lanes)
    const int ug = wave * 16 + m;
    const float wih_r = Wih[ug], wih_z = Wih[ug + 128], wih_n = Wih[ug + 256];
    const float bb_r = bih[ug]       + bhh[ug];
    const float bb_z = bih[ug + 128] + bhh[ug + 128];
    const float bi_n = bih[ug + 256];
    const float bh_n = bhh[ug + 256];
    const float bfc0 = bfc[0];
    float h_old = 0.0f;

    __syncthreads();

#pragma unroll 1
    for (int t = 0; t < Tlen; ++t) {
        float xt = sm.x[t];   // early: LDS latency hides under MFMAs

        // A fragments: every row = h (uniform-address broadcast reads)
        const float4* hp = (const float4*)sm.h[t & 1];
        hf8 A0 = bch8(hp[0 * 4 + q]);
        hf8 A1 = bch8(hp[1 * 4 + q]);
        hf8 A2 = bch8(hp[2 * 4 + q]);
        hf8 A3 = bch8(hp[3 * 4 + q]);

        // split accumulators: two independent half-chains per tile (depth 2)
        f32x4 Dxa = {0.f,0.f,0.f,0.f}, Dxb = {0.f,0.f,0.f,0.f};
        f32x4 D0a = {0.f,0.f,0.f,0.f}, D0b = {0.f,0.f,0.f,0.f};
        f32x4 D1a = {0.f,0.f,0.f,0.f}, D1b = {0.f,0.f,0.f,0.f};
        f32x4 D2a = {0.f,0.f,0.f,0.f}, D2b = {0.f,0.f,0.f,0.f};
        MFMA(Dxa, A0, Bf0); MFMA(Dxb, A1, Bf1);   // xp halves first
        MFMA(D0a, A0, Br0); MFMA(D0b, A1, Br1);
        MFMA(D1a, A0, Bz0); MFMA(D1b, A1, Bz1);
        MFMA(D2a, A0, Bn0); MFMA(D2b, A1, Bn1);
        MFMA(Dxa, A2, Bf2); MFMA(Dxb, A3, Bf3);
        MFMA(D0a, A2, Br2); MFMA(D0b, A3, Br3);
        MFMA(D1a, A2, Bz2); MFMA(D1b, A3, Bz3);
        MFMA(D2a, A2, Bn2); MFMA(D2b, A3, Bn3);

        // gates: unpredicated on all 64 lanes (q-copies identical)
        float xp  = Dxa[0] + Dxb[0];
        float xh  = xp + bfc0;
        float cur = ((xt == 128.0f) && (t != 0)) ? xh : xt;

        float r  = sigmoidf_(wih_r * cur + bb_r + (D0a[0] + D0b[0]));
        float z  = sigmoidf_(wih_z * cur + bb_z + (D1a[0] + D1b[0]));
        float n  = tanhf_(wih_n * cur + bi_n + r * ((D2a[0] + D2b[0]) + bh_n));
        float hn = (1.0f - z) * n + z * h_old;
        h_old = hn;

        if (lane < 16) sm.h[(t + 1) & 1][ug] = (__fp16)hn;
        if (tid == 0)  sm.xh[t] = xh;
        __syncthreads();
    }

    // bulk flush; cur reconstructed from pristine x + xh
    for (int i = tid; i < Tlen; i += 512) {
        float xv = sm.x[i];
        float cv = ((xv == 128.0f) && (i != 0)) ? sm.xh[i] : xv;
        out_newin[i * Bsz + b] = cv;
    }
    for (int i = tid; i < Tlen - 1; i += 512)
        out_pred[b * (Tlen - 1) + i] = sm.xh[i + 1];
}

extern "C" void kernel_launch(void* const* d_in, const int* in_sizes, int n_in,
                              void* d_out, int out_size, void* d_ws, size_t ws_size,
                              hipStream_t stream) {
    const float* x   = (const float*)d_in[0];
    const float* Wih = (const float*)d_in[1];
    const float* Whh = (const float*)d_in[2];
    const float* bih = (const float*)d_in[3];
    const float* bhh = (const float*)d_in[4];
    const float* Wfc = (const float*)d_in[5];
    const float* bfc = (const float*)d_in[6];

    float* out_newin = (float*)d_out;                 // [T*B] = 524288
    float* out_pred  = out_newin + Tlen * Bsz;        // [B*(T-1)] = 524032

    rnn_imp_kernel<<<Bsz, 512, 0, stream>>>(x, Wih, Whh, bih, bhh, Wfc, bfc,
                                            out_newin, out_pred);
}

// Round 24
// 926.099 us; speedup vs baseline: 1.1297x; 1.0743x over previous
//
#include <hip/hip_runtime.h>

#define Bsz  256
#define Tlen 2048
#define Hdim 128

typedef __fp16 hf2 __attribute__((ext_vector_type(2)));
typedef __fp16 hf8 __attribute__((ext_vector_type(8)));
typedef float  f32x4 __attribute__((ext_vector_type(4)));

// Raw-HW transcendentals (VOP1, ~1 ulp). R12-verified win.
__device__ __forceinline__ float fexp2_(float x) {
    float r; asm("v_exp_f32 %0, %1" : "=v"(r) : "v"(x)); return r;
}
__device__ __forceinline__ float frcp_(float x) {
    float r; asm("v_rcp_f32 %0, %1" : "=v"(r) : "v"(x)); return r;
}
__device__ __forceinline__ float sigmoidf_(float v) {
    return frcp_(1.0f + fexp2_(v * -1.44269504f));
}
__device__ __forceinline__ float tanhf_(float v) {
    return 1.0f - 2.0f * frcp_(fexp2_(v * 2.88539008f) + 1.0f);
}

// pack 8 consecutive f32 into a v8f16 MFMA fragment slice
__device__ __forceinline__ hf8 pack8(const float* p) {
    union { hf2 h2[4]; hf8 h8; } u;
    u.h2[0] = __builtin_amdgcn_cvt_pkrtz(p[0], p[1]);
    u.h2[1] = __builtin_amdgcn_cvt_pkrtz(p[2], p[3]);
    u.h2[2] = __builtin_amdgcn_cvt_pkrtz(p[4], p[5]);
    u.h2[3] = __builtin_amdgcn_cvt_pkrtz(p[6], p[7]);
    return u.h8;
}
__device__ __forceinline__ hf8 bch8(float4 v) { return __builtin_bit_cast(hf8, v); }

#define MFMA(D, A, B) D = __builtin_amdgcn_mfma_f32_16x16x32_f16(A, B, D, 0, 0, 0)

struct Smem {
    float  x[Tlen];       // staged input row
    float  xh[Tlen];      // staged xh outputs
    __fp16 h[2][Hdim];    // double-buffered hidden state (f16)
};

// grid = 256 blocks (1 batch row each), block = 512 threads (8 waves).
// CHAMPION STRUCTURE (R21, 929 us — locked in after R22/R23 perturbations
// regressed): uniform-A MFMA GRU step.
//  - A = h in EVERY row (D[row][col] = gh[col] for all rows): uniform-address
//    broadcast A-reads, no zero-buffer, D reg 0 valid on all 64 lanes ->
//    unpredicated gate math (only the 16-lane h-write keeps an exec mask).
//  - B = W^T tiles; weights touched ONLY by MFMA -> AGPR-native, eliminating
//    the v_accvgpr_read churn that capped all VOP-dot variants (R7-R17).
//  - Wfc in all 16 B-columns -> D3 reg 0 = xp on every lane (no readfirstlane).
//  - One barrier/step; h double-buffered in LDS (f16); outputs staged in LDS
//    and bulk-flushed post-loop (single vmcnt drain).
//  - 8 waves / 2 per SIMD: the overlap sweet spot (R16: 16 waves +37%;
//    R22: 4 waves +16%; R23 split-accumulators +7%).
// Layouts (R18-R21 HW-verified): B: lane l reg j = W[tile*16+(l&15)]
// [c*32+(l>>4)*8+j]; D: col = lane&15, reg 0 valid on all lanes (uniform A).
__global__ __launch_bounds__(512, 2)
void rnn_imp_kernel(const float* __restrict__ x,     // [B, T] (I=1)
                    const float* __restrict__ Wih,   // [384]
                    const float* __restrict__ Whh,   // [384, 128] gate-major (r,z,n)
                    const float* __restrict__ bih,   // [384]
                    const float* __restrict__ bhh,   // [384]
                    const float* __restrict__ Wfc,   // [128]
                    const float* __restrict__ bfc,   // [1]
                    float* __restrict__ out_newin,   // [T, B]
                    float* __restrict__ out_pred)    // [B, T-1]
{
    __shared__ __align__(128) Smem sm;

    const int tid  = threadIdx.x;
    const int b    = blockIdx.x;
    const int wave = tid >> 6;
    const int lane = tid & 63;
    const int m    = lane & 15;      // B/D column = unit-in-tile
    const int q    = lane >> 4;      // k-subchunk

    // stage x row (coalesced); zero h buffer 0
    for (int i = tid; i < Tlen; i += 512) sm.x[i] = x[b * Tlen + i];
    if (tid < Hdim) sm.h[0][tid] = (__fp16)0.0f;

    // ---- B fragments: W^T tiles (consumed only by MFMA -> AGPR-native) ----
    const int r0 = wave * 16 + m;            // unit row, gate r
    const int r1 = r0 + 128;                 // gate z
    const int r2 = r0 + 256;                 // gate n
    const int ko = q * 8;
    hf8 Br0, Br1, Br2, Br3, Bz0, Bz1, Bz2, Bz3,
        Bn0, Bn1, Bn2, Bn3, Bf0, Bf1, Bf2, Bf3;
    Br0 = pack8(Whh + r0 * Hdim + 0  + ko);  Br1 = pack8(Whh + r0 * Hdim + 32 + ko);
    Br2 = pack8(Whh + r0 * Hdim + 64 + ko);  Br3 = pack8(Whh + r0 * Hdim + 96 + ko);
    Bz0 = pack8(Whh + r1 * Hdim + 0  + ko);  Bz1 = pack8(Whh + r1 * Hdim + 32 + ko);
    Bz2 = pack8(Whh + r1 * Hdim + 64 + ko);  Bz3 = pack8(Whh + r1 * Hdim + 96 + ko);
    Bn0 = pack8(Whh + r2 * Hdim + 0  + ko);  Bn1 = pack8(Whh + r2 * Hdim + 32 + ko);
    Bn2 = pack8(Whh + r2 * Hdim + 64 + ko);  Bn3 = pack8(Whh + r2 * Hdim + 96 + ko);
    // Wfc in ALL columns: every lane's D3 reg 0 = xp
    Bf0 = pack8(Wfc + 0  + ko);  Bf1 = pack8(Wfc + 32 + ko);
    Bf2 = pack8(Wfc + 64 + ko);  Bf3 = pack8(Wfc + 96 + ko);

    // gate constants for this lane's column unit (valid on all lanes)
    const int ug = wave * 16 + m;
    const float wih_r = Wih[ug], wih_z = Wih[ug + 128], wih_n = Wih[ug + 256];
    const float bb_r = bih[ug]       + bhh[ug];
    const float bb_z = bih[ug + 128] + bhh[ug + 128];
    const float bi_n = bih[ug + 256];
    const float bh_n = bhh[ug + 256];
    const float bfc0 = bfc[0];
    float h_old = 0.0f;                      // per-lane copy of unit ug's state

    __syncthreads();

#pragma unroll 1
    for (int t = 0; t < Tlen; ++t) {
        // xt early: LDS latency hides under the MFMA block
        float xt = sm.x[t];

        // A fragments: every row = h (uniform-address broadcast reads)
        const float4* hp = (const float4*)sm.h[t & 1];
        hf8 A0 = bch8(hp[0 * 4 + q]);
        hf8 A1 = bch8(hp[1 * 4 + q]);
        hf8 A2 = bch8(hp[2 * 4 + q]);
        hf8 A3 = bch8(hp[3 * 4 + q]);

        f32x4 D0 = {0.f, 0.f, 0.f, 0.f};    // ghr, units wave*16+col
        f32x4 D1 = {0.f, 0.f, 0.f, 0.f};    // ghz
        f32x4 D2 = {0.f, 0.f, 0.f, 0.f};    // ghn
        f32x4 D3 = {0.f, 0.f, 0.f, 0.f};    // xp (all rows/cols)
        MFMA(D3, A0, Bf0); MFMA(D0, A0, Br0); MFMA(D1, A0, Bz0); MFMA(D2, A0, Bn0);
        MFMA(D3, A1, Bf1); MFMA(D0, A1, Br1); MFMA(D1, A1, Bz1); MFMA(D2, A1, Bn1);
        MFMA(D3, A2, Bf2); MFMA(D0, A2, Br2); MFMA(D1, A2, Bz2); MFMA(D2, A2, Bn2);
        MFMA(D3, A3, Bf3); MFMA(D0, A3, Br3); MFMA(D1, A3, Bz3); MFMA(D2, A3, Bn3);

        // gates: unpredicated on all 64 lanes (q-copies compute identical hn)
        float xp  = D3[0];
        float xh  = xp + bfc0;
        float cur = ((xt == 128.0f) && (t != 0)) ? xh : xt;

        float r  = sigmoidf_(wih_r * cur + bb_r + D0[0]);
        float z  = sigmoidf_(wih_z * cur + bb_z + D1[0]);
        float n  = tanhf_(wih_n * cur + bi_n + r * (D2[0] + bh_n));
        float hn = (1.0f - z) * n + z * h_old;
        h_old = hn;

        if (lane < 16) sm.h[(t + 1) & 1][ug] = (__fp16)hn;
        if (tid == 0)  sm.xh[t] = xh;
        __syncthreads();
    }

    // bulk flush; cur reconstructed from pristine x + xh
    for (int i = tid; i < Tlen; i += 512) {
        float xv = sm.x[i];
        float cv = ((xv == 128.0f) && (i != 0)) ? sm.xh[i] : xv;
        out_newin[i * Bsz + b] = cv;
    }
    for (int i = tid; i < Tlen - 1; i += 512)
        out_pred[b * (Tlen - 1) + i] = sm.xh[i + 1];
}

extern "C" void kernel_launch(void* const* d_in, const int* in_sizes, int n_in,
                              void* d_out, int out_size, void* d_ws, size_t ws_size,
                              hipStream_t stream) {
    const float* x   = (const float*)d_in[0];
    const float* Wih = (const float*)d_in[1];
    const float* Whh = (const float*)d_in[2];
    const float* bih = (const float*)d_in[3];
    const float* bhh = (const float*)d_in[4];
    const float* Wfc = (const float*)d_in[5];
    const float* bfc = (const float*)d_in[6];

    float* out_newin = (float*)d_out;                 // [T*B] = 524288
    float* out_pred  = out_newin + Tlen * Bsz;        // [B*(T-1)] = 524032

    rnn_imp_kernel<<<Bsz, 512, 0, stream>>>(x, Wih, Whh, bih, bhh, Wfc, bfc,
                                            out_newin, out_pred);
}